// Round 15
// baseline (99.578 us; speedup 1.0000x reference)
//
#include <hip/hip_runtime.h>
#include <hip/hip_bf16.h>

#define EMB 512
#define NHEADS 8
#define HD 64
#define SEQ 2048

typedef float f32x4 __attribute__((ext_vector_type(4)));
typedef float f32x16 __attribute__((ext_vector_type(16)));
typedef short short8 __attribute__((ext_vector_type(8)));
typedef unsigned short ushort4_t __attribute__((ext_vector_type(4)));
typedef unsigned uint2v __attribute__((ext_vector_type(2)));

#define MFMA(a, b, c)   __builtin_amdgcn_mfma_f32_16x16x32_bf16((a), (b), (c), 0, 0, 0)
#define MFMA32(a, b, c) __builtin_amdgcn_mfma_f32_32x32x16_bf16((a), (b), (c), 0, 0, 0)

__device__ inline unsigned short f2bf(float f) {
    union { float f; unsigned u; } v; v.f = f;
    unsigned r = v.u + 0x7fffu + ((v.u >> 16) & 1u);   // round-to-nearest-even
    return (unsigned short)(r >> 16);
}

__device__ inline unsigned cvt_pk_bf16(float a, float b) {
    unsigned r;
    asm("v_cvt_pk_bf16_f32 %0, %1, %2" : "=v"(r) : "v"(a), "v"(b));
    return r;  // low16 = bf16(a), high16 = bf16(b)
}

// v_permlane32_swap_b32: a[32:63] <-> b[0:31] (in place, both updated)
__device__ inline void plswap(unsigned &a, unsigned &b) {
#if __has_builtin(__builtin_amdgcn_permlane32_swap)
    uint2v r = __builtin_amdgcn_permlane32_swap(a, b, false, false);
    a = r[0]; b = r[1];
#else
    asm volatile("v_permlane32_swap_b32 %0, %1" : "+v"(a), "+v"(b));
#endif
}

__device__ inline short8 mk8(unsigned a, unsigned b, unsigned c, unsigned d) {
    union { unsigned u[4]; short8 s; } x;
    x.u[0] = a; x.u[1] = b; x.u[2] = c; x.u[3] = d;
    return x.s;
}

__device__ inline short8 f8_to_bf8(float4 a, float4 b) {
    short8 r;
    r[0] = (short)f2bf(a.x); r[1] = (short)f2bf(a.y);
    r[2] = (short)f2bf(a.z); r[3] = (short)f2bf(a.w);
    r[4] = (short)f2bf(b.x); r[5] = (short)f2bf(b.y);
    r[6] = (short)f2bf(b.z); r[7] = (short)f2bf(b.w);
    return r;
}

// ---------------------------------------------------------------------------
// Kernel 1: per-head QKV projection (unchanged from round 13, verified)
// ---------------------------------------------------------------------------
__global__ __launch_bounds__(256) void qkv_proj_kernel(
    const float* __restrict__ vin, const float* __restrict__ kin,
    const float* __restrict__ qin, const unsigned short* __restrict__ wqkvb,
    unsigned short* __restrict__ q_ws, unsigned short* __restrict__ k_ws,
    unsigned short* __restrict__ vt_ws)
{
    const int z = blockIdx.y;
    const float* __restrict__ x = (z == 0) ? qin : (z == 1 ? kin : vin);
    const unsigned short* __restrict__ wb = wqkvb + z * HD * HD;

    const int bid = blockIdx.x;
    const int st = bid & 15;
    const int h  = (bid >> 4) & 7;
    const int n  = bid >> 7;

    const int lane = threadIdx.x & 63;
    const int w    = threadIdx.x >> 6;
    const int lo = lane & 15, hi = lane >> 4;
    const int s_base = st * 128 + w * 32;

    short8 b[2][4];
#pragma unroll
    for (int nb = 0; nb < 4; ++nb)
#pragma unroll
        for (int kb = 0; kb < 2; ++kb)
            b[kb][nb] = *(const short8*)(wb + (lo + 16 * nb) * HD + kb * 32 + hi * 8);

    short8 a[2][2];
#pragma unroll
    for (int sub = 0; sub < 2; ++sub) {
        const float* xr = x + ((size_t)n * SEQ + s_base + 16 * sub + lo) * EMB + h * HD;
#pragma unroll
        for (int kb = 0; kb < 2; ++kb) {
            const float4* p = (const float4*)(xr + kb * 32 + hi * 8);
            a[sub][kb] = f8_to_bf8(p[0], p[1]);
        }
    }

    f32x4 acc[2][4];
#pragma unroll
    for (int sub = 0; sub < 2; ++sub)
#pragma unroll
        for (int nb = 0; nb < 4; ++nb) {
            f32x4 t = {0.f, 0.f, 0.f, 0.f};
            t = MFMA(a[sub][0], b[0][nb], t);
            t = MFMA(a[sub][1], b[1][nb], t);
            acc[sub][nb] = t;
        }

    const size_t nh = (size_t)n * NHEADS + h;
    if (z < 2) {
        const float sc = (z == 0) ? 0.18033688011112042f : 1.0f; // log2(e)/8
        unsigned short* o = (z == 0 ? q_ws : k_ws) + nh * SEQ * HD;
#pragma unroll
        for (int sub = 0; sub < 2; ++sub)
#pragma unroll
            for (int nb = 0; nb < 4; ++nb)
#pragma unroll
                for (int i = 0; i < 4; ++i)
                    o[(size_t)(s_base + 16 * sub + hi * 4 + i) * HD + lo + 16 * nb] =
                        f2bf(acc[sub][nb][i] * sc);
    } else {
        unsigned short* o = vt_ws + nh * HD * SEQ;
#pragma unroll
        for (int sub = 0; sub < 2; ++sub)
#pragma unroll
            for (int nb = 0; nb < 4; ++nb) {
                ushort4_t pk;
                pk[0] = f2bf(acc[sub][nb][0]); pk[1] = f2bf(acc[sub][nb][1]);
                pk[2] = f2bf(acc[sub][nb][2]); pk[3] = f2bf(acc[sub][nb][3]);
                *(ushort4_t*)(o + (size_t)(lo + 16 * nb) * SEQ + s_base + 16 * sub + hi * 4) = pk;
            }
    }
}

// ---------------------------------------------------------------------------
// Kernel 2: Wo fp32 -> bf16 (unchanged)
// ---------------------------------------------------------------------------
__global__ __launch_bounds__(256) void wconv_kernel(
    const float* __restrict__ Wo, unsigned short* __restrict__ wob)
{
    const int idx = (blockIdx.x * 256 + threadIdx.x) * 8;
    const float4* p = (const float4*)(Wo + idx);
    short8 r = f8_to_bf8(p[0], p[1]);
    *(short8*)(wob + idx) = r;
}

// ---------------------------------------------------------------------------
// Kernel 2a: Wq/Wk/Wv fp32 -> bf16, packed [z][64][64] (unchanged)
// ---------------------------------------------------------------------------
__global__ __launch_bounds__(256) void wqkvconv_kernel(
    const float* __restrict__ Wq, const float* __restrict__ Wk,
    const float* __restrict__ Wv, unsigned short* __restrict__ wqkvb)
{
    const int idx = (blockIdx.x * 256 + threadIdx.x) * 8;
    const float* src = (idx < 4096) ? (Wq + idx)
                     : (idx < 8192) ? (Wk + idx - 4096)
                                    : (Wv + idx - 8192);
    const float4* p = (const float4*)src;
    short8 r = f8_to_bf8(p[0], p[1]);
    *(short8*)(wqkvb + idx) = r;
}

// ---------------------------------------------------------------------------
// Kernel 2b: per-(n, 64-key-tile) mask-zero flags (unchanged)
// ---------------------------------------------------------------------------
__global__ __launch_bounds__(64) void maskflags_kernel(
    const int* __restrict__ mask, unsigned* __restrict__ flags)
{
    const int n = blockIdx.x;
    const int t = threadIdx.x;
    bool has0 = false;
    if (t < 32) {
        const int* mrow = mask + (size_t)n * SEQ + t * 64;
#pragma unroll 4
        for (int j = 0; j < 64; j += 4) {
            int4 m4 = *(const int4*)(mrow + j);
            has0 |= (m4.x == 0) | (m4.y == 0) | (m4.z == 0) | (m4.w == 0);
        }
    }
    unsigned long long b = __ballot(has0);
    if (t == 0) flags[n] = (unsigned)(b & 0xffffffffu);
}

// ---------------------------------------------------------------------------
// Kernel 3: flash attention v4 — same compute core as verified round 14
// (32x32x16 MFMA, in-register P via cvt_pk + permlane32_swap), but
// 256-thread blocks (4 waves), grid 512 -> TWO independent blocks per CU.
// Rationale: R14's 8-wave single-block convoy serialized the MFMA/VALU/LDS
// pipes (wall ~= sum of pipes); two barrier-independent blocks per CU let
// one block's compute fill pipes while the other sits at its barrier.
// Staging: each thread now stages 2 rows per array (256 threads, 64 rows).
// ---------------------------------------------------------------------------
__global__ __launch_bounds__(256, 2) void attn_kernel(
    const unsigned short* __restrict__ q_ws, const unsigned short* __restrict__ k_ws,
    const unsigned short* __restrict__ vt_ws, const int* __restrict__ mask,
    const unsigned* __restrict__ flags, unsigned short* __restrict__ ao_ws)
{
    __shared__ __align__(16) unsigned short klds[64][72];  // [key][d], padded
    __shared__ __align__(16) unsigned short vlds[64][72];  // [d][key], padded
    __shared__ __align__(16) int            mlds[64];
    __shared__ __align__(16) float          llds[4][32];

    const int tid  = threadIdx.x;
    const int lane = tid & 63;
    const int w    = tid >> 6;                  // 0..3
    const int l31  = lane & 31;
    const int hi5  = lane >> 5;                 // 0..1
    // XCD swizzle, grid=512 (bijective): 64 blocks/XCD; each (n,h)'s 16
    // blocks and 512KB K/V stream pinned to one XCD's L2.
    const int bid = (blockIdx.x & 7) * 64 + (blockIdx.x >> 3);
    const int wid = bid * 4 + w;
    const int qb  = wid & 63;          // 32-row q-block (S/32 = 64)
    const int h   = (wid >> 6) & 7;
    const int n   = wid >> 9;
    const size_t nh = (size_t)n * NHEADS + h;

    const unsigned short* qp = q_ws + nh * SEQ * HD;
    const unsigned short* kp = k_ws + nh * SEQ * HD;
    const unsigned short* vp = vt_ws + nh * HD * SEQ;
    const int* mp = mask + (size_t)n * SEQ;
    const unsigned fl = flags[n];

    const int q0 = qb * 32;
    // Q as B-fragments: bq[s] = Q[q0 + l31][16s + 8*hi5 .. +7]
    short8 bq[4];
#pragma unroll
    for (int s = 0; s < 4; ++s)
        bq[s] = *(const short8*)(qp + (size_t)(q0 + l31) * HD + 16 * s + 8 * hi5);

    f32x16 o0, o1;
#pragma unroll
    for (int r = 0; r < 16; ++r) { o0[r] = 0.f; o1[r] = 0.f; }
    float lacc = 0.f;

    // staging: 256 threads cover 64 rows x 8 col-chunks with 2 rows/thread
    const int sr = tid >> 3;                  // 0..31
    const int sc = (tid & 7) * 8;
    short8 rk0 = *(const short8*)(kp + (size_t)sr * HD + sc);
    short8 rk1 = *(const short8*)(kp + (size_t)(sr + 32) * HD + sc);
    short8 rv0 = *(const short8*)(vp + (size_t)sr * SEQ + sc);
    short8 rv1 = *(const short8*)(vp + (size_t)(sr + 32) * SEQ + sc);
    int    rm  = (w == 0) ? mp[lane] : 0;

    for (int t = 0; t < 32; ++t) {
        const int kt = t * 64;
        __syncthreads();                      // (A) done reading tile t-1
        *(short8*)(&klds[sr][sc])      = rk0;
        *(short8*)(&klds[sr + 32][sc]) = rk1;
        *(short8*)(&vlds[sr][sc])      = rv0;
        *(short8*)(&vlds[sr + 32][sc]) = rv1;
        if (w == 0) mlds[lane] = rm;
        __syncthreads();                      // (B) tile t visible

        if (t < 31) {                         // prefetch tile t+1
            const int ktn = kt + 64;
            rk0 = *(const short8*)(kp + (size_t)(ktn + sr) * HD + sc);
            rk1 = *(const short8*)(kp + (size_t)(ktn + sr + 32) * HD + sc);
            rv0 = *(const short8*)(vp + (size_t)sr * SEQ + ktn + sc);
            rv1 = *(const short8*)(vp + (size_t)(sr + 32) * SEQ + ktn + sc);
            rm  = (w == 0) ? mp[ktn + lane] : 0;
        }

        const bool masked = (fl >> t) & 1u;
        short8 pa[4];                         // PV A-fragments (keys 0..63)
#pragma unroll
        for (int kb = 0; kb < 2; ++kb) {
            // S^T = K Q^T : D[key = 32kb + row][q = l31]
            f32x16 e;
#pragma unroll
            for (int r = 0; r < 16; ++r) e[r] = 0.f;
#pragma unroll
            for (int s = 0; s < 4; ++s) {
                short8 ak = *(const short8*)(&klds[32 * kb + l31][16 * s + 8 * hi5]);
                e = MFMA32(ak, bq[s], e);
            }
            if (masked) {
#pragma unroll
                for (int r = 0; r < 16; ++r) {
                    const int key = 32 * kb + (r & 3) + 8 * (r >> 2) + 4 * hi5;
                    if (mlds[key] == 0) e[r] = -1e30f;
                }
            }
            // no-max softmax + pack: wv[r2] = bf16x2 of key pair
            unsigned wv[8];
#pragma unroll
            for (int r2 = 0; r2 < 8; ++r2) {
                float p0 = __builtin_amdgcn_exp2f(e[2 * r2]);
                float p1 = __builtin_amdgcn_exp2f(e[2 * r2 + 1]);
                lacc += p0 + p1;
                wv[r2] = cvt_pk_bf16(p0, p1);
            }
            // in-place half-swap -> words land in PV A-fragment order
            plswap(wv[0], wv[2]); plswap(wv[1], wv[3]);
            plswap(wv[4], wv[6]); plswap(wv[5], wv[7]);
            pa[2 * kb]     = mk8(wv[0], wv[1], wv[2], wv[3]);
            pa[2 * kb + 1] = mk8(wv[4], wv[5], wv[6], wv[7]);
        }
        // O += P V  (B-fragments from vlds; d-blocks 0 and 1)
#pragma unroll
        for (int s = 0; s < 4; ++s) {
            short8 bv0 = *(const short8*)(&vlds[l31][16 * s + 8 * hi5]);
            short8 bv1 = *(const short8*)(&vlds[32 + l31][16 * s + 8 * hi5]);
            o0 = MFMA32(pa[s], bv0, o0);
            o1 = MFMA32(pa[s], bv1, o1);
        }
    }

    // l: lane holds partial for q = l31 (its 16 key-rows); partner has rest
    lacc += __shfl_xor(lacc, 32);
    if (lane < 32) llds[w][lane] = 1.0f / lacc;   // same-wave, in-order

    unsigned short* op = ao_ws + ((size_t)n * SEQ + q0) * EMB + h * HD;
#pragma unroll
    for (int r = 0; r < 16; ++r) {
        const int qrow = (r & 3) + 8 * (r >> 2) + 4 * hi5;
        const float linv = llds[w][qrow];
        op[(size_t)qrow * EMB + l31]      = f2bf(o0[r] * linv);
        op[(size_t)qrow * EMB + 32 + l31] = f2bf(o1[r] * linv);
    }
}

// ---------------------------------------------------------------------------
// Kernel 4: output projection (unchanged from round 13, verified)
// ---------------------------------------------------------------------------
__global__ __launch_bounds__(256) void out_proj_kernel(
    const unsigned short* __restrict__ ao_ws, const unsigned short* __restrict__ wob,
    const float* __restrict__ bo, float* __restrict__ out)
{
    const int bid = blockIdx.x;
    const int nc = bid & 7;
    const int mt = bid >> 3;
    const int lane = threadIdx.x & 63;
    const int w = threadIdx.x >> 6;
    const int lo = lane & 15, hi = lane >> 4;
    const int m0 = mt * 128 + w * 32;
    const int e0 = nc * 64;

    f32x4 acc[2][4];
#pragma unroll
    for (int sub = 0; sub < 2; ++sub)
#pragma unroll
        for (int nb = 0; nb < 4; ++nb)
            acc[sub][nb] = (f32x4){0.f, 0.f, 0.f, 0.f};

    const unsigned short* ar0 = ao_ws + (size_t)(m0 + lo) * EMB;
    const unsigned short* ar1 = ao_ws + (size_t)(m0 + 16 + lo) * EMB;
    for (int k0 = 0; k0 < EMB; k0 += 32) {
        short8 a0 = *(const short8*)(ar0 + k0 + hi * 8);
        short8 a1 = *(const short8*)(ar1 + k0 + hi * 8);
#pragma unroll
        for (int nb = 0; nb < 4; ++nb) {
            short8 b = *(const short8*)(wob + (size_t)(e0 + lo + 16 * nb) * EMB + k0 + hi * 8);
            acc[0][nb] = MFMA(a0, b, acc[0][nb]);
            acc[1][nb] = MFMA(a1, b, acc[1][nb]);
        }
    }
#pragma unroll
    for (int sub = 0; sub < 2; ++sub)
#pragma unroll
        for (int nb = 0; nb < 4; ++nb) {
            float bias = bo[e0 + lo + 16 * nb];
#pragma unroll
            for (int i = 0; i < 4; ++i)
                out[(size_t)(m0 + 16 * sub + hi * 4 + i) * EMB + e0 + lo + 16 * nb] =
                    acc[sub][nb][i] + bias;
        }
}

// ---------------------------------------------------------------------------
extern "C" void kernel_launch(void* const* d_in, const int* in_sizes, int n_in,
                              void* d_out, int out_size, void* d_ws, size_t ws_size,
                              hipStream_t stream)
{
    const float* vin = (const float*)d_in[0];
    const float* kin = (const float*)d_in[1];
    const float* qin = (const float*)d_in[2];
    const int*  mask = (const int*)d_in[3];
    const float* Wv  = (const float*)d_in[4];
    const float* Wk  = (const float*)d_in[5];
    const float* Wq  = (const float*)d_in[6];
    const float* Wo  = (const float*)d_in[7];
    const float* bo  = (const float*)d_in[8];
    float* out = (float*)d_out;

    const int N = in_sizes[0] / (SEQ * EMB);   // 4

    char* ws = (char*)d_ws;
    const size_t qkv_bytes = (size_t)N * NHEADS * SEQ * HD * 2;  // 8.39 MB each
    unsigned short* q_ws  = (unsigned short*)(ws);
    unsigned short* k_ws  = (unsigned short*)(ws + qkv_bytes);
    unsigned short* vt_ws = (unsigned short*)(ws + 2 * qkv_bytes);
    unsigned short* ao_ws = (unsigned short*)(ws + 3 * qkv_bytes);
    unsigned short* wob   = (unsigned short*)(ws + 4 * qkv_bytes);
    unsigned*       flags = (unsigned*)(ws + 4 * qkv_bytes + (size_t)EMB * EMB * 2);
    unsigned short* wqkvb = (unsigned short*)(ws + 4 * qkv_bytes + (size_t)EMB * EMB * 2 + 4096);

    hipLaunchKernelGGL(wconv_kernel, dim3(EMB * EMB / 2048), dim3(256), 0, stream,
                       Wo, wob);
    hipLaunchKernelGGL(wqkvconv_kernel, dim3(6), dim3(256), 0, stream,
                       Wq, Wk, Wv, wqkvb);
    hipLaunchKernelGGL(maskflags_kernel, dim3(N), dim3(64), 0, stream,
                       mask, flags);
    hipLaunchKernelGGL(qkv_proj_kernel, dim3(N * NHEADS * (SEQ / 128), 3), dim3(256), 0, stream,
                       vin, kin, qin, wqkvb, q_ws, k_ws, vt_ws);
    hipLaunchKernelGGL(attn_kernel, dim3(N * NHEADS * (SEQ / 32) / 4), dim3(256), 0, stream,
                       q_ws, k_ws, vt_ws, mask, flags, ao_ws);
    hipLaunchKernelGGL(out_proj_kernel, dim3((N * SEQ / 128) * (EMB / 64)), dim3(256), 0, stream,
                       ao_ws, wob, bo, out);
}

// Round 16
// 90.495 us; speedup vs baseline: 1.1004x; 1.1004x over previous
//
#include <hip/hip_runtime.h>
#include <hip/hip_bf16.h>

#define EMB 512
#define NHEADS 8
#define HD 64
#define SEQ 2048

typedef float f32x4 __attribute__((ext_vector_type(4)));
typedef float f32x16 __attribute__((ext_vector_type(16)));
typedef short short8 __attribute__((ext_vector_type(8)));
typedef unsigned short ushort4_t __attribute__((ext_vector_type(4)));
typedef unsigned uint2v __attribute__((ext_vector_type(2)));

#define MFMA(a, b, c)   __builtin_amdgcn_mfma_f32_16x16x32_bf16((a), (b), (c), 0, 0, 0)
#define MFMA32(a, b, c) __builtin_amdgcn_mfma_f32_32x32x16_bf16((a), (b), (c), 0, 0, 0)

__device__ inline unsigned short f2bf(float f) {
    union { float f; unsigned u; } v; v.f = f;
    unsigned r = v.u + 0x7fffu + ((v.u >> 16) & 1u);   // round-to-nearest-even
    return (unsigned short)(r >> 16);
}

__device__ inline unsigned cvt_pk_bf16(float a, float b) {
    unsigned r;
    asm("v_cvt_pk_bf16_f32 %0, %1, %2" : "=v"(r) : "v"(a), "v"(b));
    return r;  // low16 = bf16(a), high16 = bf16(b)
}

// v_permlane32_swap_b32: a[32:63] <-> b[0:31] (in place, both updated)
__device__ inline void plswap(unsigned &a, unsigned &b) {
#if __has_builtin(__builtin_amdgcn_permlane32_swap)
    uint2v r = __builtin_amdgcn_permlane32_swap(a, b, false, false);
    a = r[0]; b = r[1];
#else
    asm volatile("v_permlane32_swap_b32 %0, %1" : "+v"(a), "+v"(b));
#endif
}

__device__ inline short8 mk8(unsigned a, unsigned b, unsigned c, unsigned d) {
    union { unsigned u[4]; short8 s; } x;
    x.u[0] = a; x.u[1] = b; x.u[2] = c; x.u[3] = d;
    return x.s;
}

__device__ inline short8 f8_to_bf8(float4 a, float4 b) {
    short8 r;
    r[0] = (short)f2bf(a.x); r[1] = (short)f2bf(a.y);
    r[2] = (short)f2bf(a.z); r[3] = (short)f2bf(a.w);
    r[4] = (short)f2bf(b.x); r[5] = (short)f2bf(b.y);
    r[6] = (short)f2bf(b.z); r[7] = (short)f2bf(b.w);
    return r;
}

// ---------------------------------------------------------------------------
// Kernel 1: per-head QKV projection (unchanged from round 13, verified)
// ---------------------------------------------------------------------------
__global__ __launch_bounds__(256) void qkv_proj_kernel(
    const float* __restrict__ vin, const float* __restrict__ kin,
    const float* __restrict__ qin, const unsigned short* __restrict__ wqkvb,
    unsigned short* __restrict__ q_ws, unsigned short* __restrict__ k_ws,
    unsigned short* __restrict__ vt_ws)
{
    const int z = blockIdx.y;
    const float* __restrict__ x = (z == 0) ? qin : (z == 1 ? kin : vin);
    const unsigned short* __restrict__ wb = wqkvb + z * HD * HD;

    const int bid = blockIdx.x;
    const int st = bid & 15;
    const int h  = (bid >> 4) & 7;
    const int n  = bid >> 7;

    const int lane = threadIdx.x & 63;
    const int w    = threadIdx.x >> 6;
    const int lo = lane & 15, hi = lane >> 4;
    const int s_base = st * 128 + w * 32;

    short8 b[2][4];
#pragma unroll
    for (int nb = 0; nb < 4; ++nb)
#pragma unroll
        for (int kb = 0; kb < 2; ++kb)
            b[kb][nb] = *(const short8*)(wb + (lo + 16 * nb) * HD + kb * 32 + hi * 8);

    short8 a[2][2];
#pragma unroll
    for (int sub = 0; sub < 2; ++sub) {
        const float* xr = x + ((size_t)n * SEQ + s_base + 16 * sub + lo) * EMB + h * HD;
#pragma unroll
        for (int kb = 0; kb < 2; ++kb) {
            const float4* p = (const float4*)(xr + kb * 32 + hi * 8);
            a[sub][kb] = f8_to_bf8(p[0], p[1]);
        }
    }

    f32x4 acc[2][4];
#pragma unroll
    for (int sub = 0; sub < 2; ++sub)
#pragma unroll
        for (int nb = 0; nb < 4; ++nb) {
            f32x4 t = {0.f, 0.f, 0.f, 0.f};
            t = MFMA(a[sub][0], b[0][nb], t);
            t = MFMA(a[sub][1], b[1][nb], t);
            acc[sub][nb] = t;
        }

    const size_t nh = (size_t)n * NHEADS + h;
    if (z < 2) {
        const float sc = (z == 0) ? 0.18033688011112042f : 1.0f; // log2(e)/8
        unsigned short* o = (z == 0 ? q_ws : k_ws) + nh * SEQ * HD;
#pragma unroll
        for (int sub = 0; sub < 2; ++sub)
#pragma unroll
            for (int nb = 0; nb < 4; ++nb)
#pragma unroll
                for (int i = 0; i < 4; ++i)
                    o[(size_t)(s_base + 16 * sub + hi * 4 + i) * HD + lo + 16 * nb] =
                        f2bf(acc[sub][nb][i] * sc);
    } else {
        unsigned short* o = vt_ws + nh * HD * SEQ;
#pragma unroll
        for (int sub = 0; sub < 2; ++sub)
#pragma unroll
            for (int nb = 0; nb < 4; ++nb) {
                ushort4_t pk;
                pk[0] = f2bf(acc[sub][nb][0]); pk[1] = f2bf(acc[sub][nb][1]);
                pk[2] = f2bf(acc[sub][nb][2]); pk[3] = f2bf(acc[sub][nb][3]);
                *(ushort4_t*)(o + (size_t)(lo + 16 * nb) * SEQ + s_base + 16 * sub + hi * 4) = pk;
            }
    }
}

// ---------------------------------------------------------------------------
// Kernel 2: fused prologue — Wo conv (blocks 0..127), Wqkv conv (128..133),
// mask flags (134..134+N-1). One launch instead of three.
// ---------------------------------------------------------------------------
__global__ __launch_bounds__(256) void prep_kernel(
    const float* __restrict__ Wo, unsigned short* __restrict__ wob,
    const float* __restrict__ Wq, const float* __restrict__ Wk,
    const float* __restrict__ Wv, unsigned short* __restrict__ wqkvb,
    const int* __restrict__ mask, unsigned* __restrict__ flags)
{
    const int b = blockIdx.x;
    if (b < 128) {
        const int idx = (b * 256 + threadIdx.x) * 8;
        const float4* p = (const float4*)(Wo + idx);
        *(short8*)(wob + idx) = f8_to_bf8(p[0], p[1]);
    } else if (b < 134) {
        const int idx = ((b - 128) * 256 + threadIdx.x) * 8;   // 0..12287
        const float* src = (idx < 4096) ? (Wq + idx)
                         : (idx < 8192) ? (Wk + idx - 4096)
                                        : (Wv + idx - 8192);
        const float4* p = (const float4*)src;
        *(short8*)(wqkvb + idx) = f8_to_bf8(p[0], p[1]);
    } else {
        const int n = b - 134;
        const int t = threadIdx.x;
        if (t < 64) {                       // wave 0 only
            bool has0 = false;
            if (t < 32) {
                const int* mrow = mask + (size_t)n * SEQ + t * 64;
#pragma unroll 4
                for (int j = 0; j < 64; j += 4) {
                    int4 m4 = *(const int4*)(mrow + j);
                    has0 |= (m4.x == 0) | (m4.y == 0) | (m4.z == 0) | (m4.w == 0);
                }
            }
            unsigned long long bl = __ballot(has0);
            if (t == 0) flags[n] = (unsigned)(bl & 0xffffffffu);
        }
    }
}

// ---------------------------------------------------------------------------
// Kernel 3: flash attention — byte-identical compute to round 14 (verified,
// 43.5us): 512 threads / 8 waves, grid 256 (1 block/CU so all 8 waves share
// one staged K/V tile), 32x32x16 MFMA, in-register P via cvt_pk +
// permlane32_swap, single-buffer 2-barrier staging with register prefetch.
// ---------------------------------------------------------------------------
__global__ __launch_bounds__(512, 1) void attn_kernel(
    const unsigned short* __restrict__ q_ws, const unsigned short* __restrict__ k_ws,
    const unsigned short* __restrict__ vt_ws, const int* __restrict__ mask,
    const unsigned* __restrict__ flags, unsigned short* __restrict__ ao_ws)
{
    __shared__ __align__(16) unsigned short klds[64][72];  // [key][d], padded
    __shared__ __align__(16) unsigned short vlds[64][72];  // [d][key], padded
    __shared__ __align__(16) int            mlds[64];
    __shared__ __align__(16) float          llds[8][32];

    const int tid  = threadIdx.x;
    const int lane = tid & 63;
    const int w    = tid >> 6;                  // 0..7
    const int l31  = lane & 31;
    const int hi5  = lane >> 5;                 // 0..1
    // XCD swizzle, grid=256 (bijective): 32 blocks/XCD
    const int bid = (blockIdx.x & 7) * 32 + (blockIdx.x >> 3);
    const int wid = bid * 8 + w;
    const int qb  = wid & 63;          // 32-row q-block (S/32 = 64)
    const int h   = (wid >> 6) & 7;
    const int n   = wid >> 9;
    const size_t nh = (size_t)n * NHEADS + h;

    const unsigned short* qp = q_ws + nh * SEQ * HD;
    const unsigned short* kp = k_ws + nh * SEQ * HD;
    const unsigned short* vp = vt_ws + nh * HD * SEQ;
    const int* mp = mask + (size_t)n * SEQ;
    const unsigned fl = flags[n];

    const int q0 = qb * 32;
    // Q as B-fragments: bq[s] = Q[q0 + l31][16s + 8*hi5 .. +7]
    short8 bq[4];
#pragma unroll
    for (int s = 0; s < 4; ++s)
        bq[s] = *(const short8*)(qp + (size_t)(q0 + l31) * HD + 16 * s + 8 * hi5);

    f32x16 o0, o1;
#pragma unroll
    for (int r = 0; r < 16; ++r) { o0[r] = 0.f; o1[r] = 0.f; }
    float lacc = 0.f;

    // staging: 512 threads cover 64 rows x 8 col-chunks
    const int sr = tid >> 3;
    const int sc = (tid & 7) * 8;
    short8 rk = *(const short8*)(kp + (size_t)sr * HD + sc);
    short8 rv = *(const short8*)(vp + (size_t)sr * SEQ + sc);
    int    rm = (w == 0) ? mp[lane] : 0;

    for (int t = 0; t < 32; ++t) {
        const int kt = t * 64;
        __syncthreads();                      // (A) done reading tile t-1
        *(short8*)(&klds[sr][sc]) = rk;
        *(short8*)(&vlds[sr][sc]) = rv;
        if (w == 0) mlds[lane] = rm;
        __syncthreads();                      // (B) tile t visible

        if (t < 31) {                         // prefetch tile t+1
            const int ktn = kt + 64;
            rk = *(const short8*)(kp + (size_t)(ktn + sr) * HD + sc);
            rv = *(const short8*)(vp + (size_t)sr * SEQ + ktn + sc);
            rm = (w == 0) ? mp[ktn + lane] : 0;
        }

        const bool masked = (fl >> t) & 1u;
        short8 pa[4];                         // PV A-fragments (keys 0..63)
#pragma unroll
        for (int kb = 0; kb < 2; ++kb) {
            // S^T = K Q^T : D[key = 32kb + row][q = l31]
            f32x16 e;
#pragma unroll
            for (int r = 0; r < 16; ++r) e[r] = 0.f;
#pragma unroll
            for (int s = 0; s < 4; ++s) {
                short8 ak = *(const short8*)(&klds[32 * kb + l31][16 * s + 8 * hi5]);
                e = MFMA32(ak, bq[s], e);
            }
            if (masked) {
#pragma unroll
                for (int r = 0; r < 16; ++r) {
                    const int key = 32 * kb + (r & 3) + 8 * (r >> 2) + 4 * hi5;
                    if (mlds[key] == 0) e[r] = -1e30f;
                }
            }
            // no-max softmax + pack: wv[r2] = bf16x2 of key pair
            unsigned wv[8];
#pragma unroll
            for (int r2 = 0; r2 < 8; ++r2) {
                float p0 = __builtin_amdgcn_exp2f(e[2 * r2]);
                float p1 = __builtin_amdgcn_exp2f(e[2 * r2 + 1]);
                lacc += p0 + p1;
                wv[r2] = cvt_pk_bf16(p0, p1);
            }
            // in-place half-swap -> words land in PV A-fragment order
            plswap(wv[0], wv[2]); plswap(wv[1], wv[3]);
            plswap(wv[4], wv[6]); plswap(wv[5], wv[7]);
            pa[2 * kb]     = mk8(wv[0], wv[1], wv[2], wv[3]);
            pa[2 * kb + 1] = mk8(wv[4], wv[5], wv[6], wv[7]);
        }
        // O += P V  (B-fragments from vlds; d-blocks 0 and 1)
#pragma unroll
        for (int s = 0; s < 4; ++s) {
            short8 bv0 = *(const short8*)(&vlds[l31][16 * s + 8 * hi5]);
            short8 bv1 = *(const short8*)(&vlds[32 + l31][16 * s + 8 * hi5]);
            o0 = MFMA32(pa[s], bv0, o0);
            o1 = MFMA32(pa[s], bv1, o1);
        }
    }

    // l: lane holds partial for q = l31 (its 16 key-rows); partner has rest
    lacc += __shfl_xor(lacc, 32);
    if (lane < 32) llds[w][lane] = 1.0f / lacc;   // same-wave, in-order

    unsigned short* op = ao_ws + ((size_t)n * SEQ + q0) * EMB + h * HD;
#pragma unroll
    for (int r = 0; r < 16; ++r) {
        const int qrow = (r & 3) + 8 * (r >> 2) + 4 * hi5;
        const float linv = llds[w][qrow];
        op[(size_t)qrow * EMB + l31]      = f2bf(o0[r] * linv);
        op[(size_t)qrow * EMB + 32 + l31] = f2bf(o1[r] * linv);
    }
}

// ---------------------------------------------------------------------------
// Kernel 4: output projection. Compute identical to round 13 (verified);
// NEW: bijective XCD swizzle so the 8 blocks sharing each 128KB A-panel
// (same mt, 8 nc) land on ONE XCD's L2 instead of being scattered across
// all 8 (A-panel refetch traffic ~8x down).
// ---------------------------------------------------------------------------
__global__ __launch_bounds__(256) void out_proj_kernel(
    const unsigned short* __restrict__ ao_ws, const unsigned short* __restrict__ wob,
    const float* __restrict__ bo, float* __restrict__ out)
{
    // grid = 512 (multiple of 8): phys block p -> XCD p%8; logical id below
    // gives each XCD a contiguous run of 64 logical blocks = 8 whole panels.
    const int swz = (blockIdx.x & 7) * 64 + (blockIdx.x >> 3);
    const int nc = swz & 7;
    const int mt = swz >> 3;
    const int lane = threadIdx.x & 63;
    const int w = threadIdx.x >> 6;
    const int lo = lane & 15, hi = lane >> 4;
    const int m0 = mt * 128 + w * 32;
    const int e0 = nc * 64;

    f32x4 acc[2][4];
#pragma unroll
    for (int sub = 0; sub < 2; ++sub)
#pragma unroll
        for (int nb = 0; nb < 4; ++nb)
            acc[sub][nb] = (f32x4){0.f, 0.f, 0.f, 0.f};

    const unsigned short* ar0 = ao_ws + (size_t)(m0 + lo) * EMB;
    const unsigned short* ar1 = ao_ws + (size_t)(m0 + 16 + lo) * EMB;
    for (int k0 = 0; k0 < EMB; k0 += 32) {
        short8 a0 = *(const short8*)(ar0 + k0 + hi * 8);
        short8 a1 = *(const short8*)(ar1 + k0 + hi * 8);
#pragma unroll
        for (int nb = 0; nb < 4; ++nb) {
            short8 b = *(const short8*)(wob + (size_t)(e0 + lo + 16 * nb) * EMB + k0 + hi * 8);
            acc[0][nb] = MFMA(a0, b, acc[0][nb]);
            acc[1][nb] = MFMA(a1, b, acc[1][nb]);
        }
    }
#pragma unroll
    for (int sub = 0; sub < 2; ++sub)
#pragma unroll
        for (int nb = 0; nb < 4; ++nb) {
            float bias = bo[e0 + lo + 16 * nb];
#pragma unroll
            for (int i = 0; i < 4; ++i)
                out[(size_t)(m0 + 16 * sub + hi * 4 + i) * EMB + e0 + lo + 16 * nb] =
                    acc[sub][nb][i] + bias;
        }
}

// ---------------------------------------------------------------------------
extern "C" void kernel_launch(void* const* d_in, const int* in_sizes, int n_in,
                              void* d_out, int out_size, void* d_ws, size_t ws_size,
                              hipStream_t stream)
{
    const float* vin = (const float*)d_in[0];
    const float* kin = (const float*)d_in[1];
    const float* qin = (const float*)d_in[2];
    const int*  mask = (const int*)d_in[3];
    const float* Wv  = (const float*)d_in[4];
    const float* Wk  = (const float*)d_in[5];
    const float* Wq  = (const float*)d_in[6];
    const float* Wo  = (const float*)d_in[7];
    const float* bo  = (const float*)d_in[8];
    float* out = (float*)d_out;

    const int N = in_sizes[0] / (SEQ * EMB);   // 4

    char* ws = (char*)d_ws;
    const size_t qkv_bytes = (size_t)N * NHEADS * SEQ * HD * 2;  // 8.39 MB each
    unsigned short* q_ws  = (unsigned short*)(ws);
    unsigned short* k_ws  = (unsigned short*)(ws + qkv_bytes);
    unsigned short* vt_ws = (unsigned short*)(ws + 2 * qkv_bytes);
    unsigned short* ao_ws = (unsigned short*)(ws + 3 * qkv_bytes);
    unsigned short* wob   = (unsigned short*)(ws + 4 * qkv_bytes);
    unsigned*       flags = (unsigned*)(ws + 4 * qkv_bytes + (size_t)EMB * EMB * 2);
    unsigned short* wqkvb = (unsigned short*)(ws + 4 * qkv_bytes + (size_t)EMB * EMB * 2 + 4096);

    hipLaunchKernelGGL(prep_kernel, dim3(134 + N), dim3(256), 0, stream,
                       Wo, wob, Wq, Wk, Wv, wqkvb, mask, flags);
    hipLaunchKernelGGL(qkv_proj_kernel, dim3(N * NHEADS * (SEQ / 128), 3), dim3(256), 0, stream,
                       vin, kin, qin, wqkvb, q_ws, k_ws, vt_ws);
    hipLaunchKernelGGL(attn_kernel, dim3(N * NHEADS * (SEQ / 32) / 8), dim3(512), 0, stream,
                       q_ws, k_ws, vt_ws, mask, flags, ao_ws);
    hipLaunchKernelGGL(out_proj_kernel, dim3((N * SEQ / 128) * (EMB / 64)), dim3(256), 0, stream,
                       ao_ws, wob, bo, out);
}